// Round 8
// baseline (686.651 us; speedup 1.0000x reference)
//
#include <hip/hip_runtime.h>
#include <math.h>

#define NT 256
typedef unsigned short u16;
typedef __attribute__((ext_vector_type(8))) u16 u16x8;
typedef __attribute__((ext_vector_type(4))) u16 u16x4;
typedef __attribute__((ext_vector_type(8))) short bf16x8;
typedef __attribute__((ext_vector_type(4))) float f32x4;
typedef __attribute__((ext_vector_type(2))) float f32x2;

// PC row layout (stride 384 B): [0,128) fp8-e4m3 P (score side) | [128,384) bf16 cur (value side)
#define PCS 384

__device__ __forceinline__ float bf2f(u16 h) {
  union { unsigned u; float f; } v;
  v.u = ((unsigned)h) << 16;
  return v.f;
}
__device__ __forceinline__ u16 f2bf(float f) {
  union { float f; unsigned u; } v;
  v.f = f;
  unsigned r = v.u + 0x7FFFu + ((v.u >> 16) & 1u);
  return (u16)(r >> 16);
}

// ---------------- CSR build (combined entity+user) ----------------
__global__ __launch_bounds__(NT) void k_hist(const int* __restrict__ head, int n_kg,
                                             const int* __restrict__ usr, int n_ui,
                                             int* __restrict__ deg, int n_ent) {
  int i = blockIdx.x * NT + threadIdx.x;
  if (i < n_kg) atomicAdd(&deg[head[i]], 1);
  if (i < n_ui) atomicAdd(&deg[n_ent + usr[i]], 1);
}

__global__ __launch_bounds__(NT) void k_scan1(const int* __restrict__ in, int* __restrict__ out,
                                              int* __restrict__ aux, int n) {
  __shared__ int sd[NT];
  int t = threadIdx.x;
  int base = blockIdx.x * (NT * 8) + t * 8;
  int v[8], ex[8];
  int run = 0;
#pragma unroll
  for (int j = 0; j < 8; ++j) {
    v[j] = (base + j < n) ? in[base + j] : 0;
    ex[j] = run;
    run += v[j];
  }
  sd[t] = run;
  __syncthreads();
  for (int off = 1; off < NT; off <<= 1) {
    int x = (t >= off) ? sd[t - off] : 0;
    __syncthreads();
    sd[t] += x;
    __syncthreads();
  }
  int texcl = sd[t] - run;
#pragma unroll
  for (int j = 0; j < 8; ++j)
    if (base + j < n) out[base + j] = texcl + ex[j];
  if (t == NT - 1) aux[blockIdx.x] = sd[NT - 1];
}

__global__ __launch_bounds__(NT) void k_scan2(int* __restrict__ aux, int nb) {
  __shared__ int sd[NT];
  int t = threadIdx.x;
  int v = (t < nb) ? aux[t] : 0;
  sd[t] = v;
  __syncthreads();
  for (int off = 1; off < NT; off <<= 1) {
    int x = (t >= off) ? sd[t - off] : 0;
    __syncthreads();
    sd[t] += x;
    __syncthreads();
  }
  if (t < nb) aux[t] = sd[t] - v;  // exclusive
}

__global__ __launch_bounds__(NT) void k_scan3(int* __restrict__ out, int* __restrict__ cur,
                                              const int* __restrict__ aux, int n) {
  int base = blockIdx.x * (NT * 8) + threadIdx.x * 8;
  int add = aux[blockIdx.x];
#pragma unroll
  for (int j = 0; j < 8; ++j)
    if (base + j < n) {
      int v = out[base + j] + add;
      out[base + j] = v;
      cur[base + j] = v;
    }
}

__global__ __launch_bounds__(NT) void k_scatter(
    const int* __restrict__ head, const int* __restrict__ tail, const int* __restrict__ etype, int n_kg,
    const int* __restrict__ usr, const int* __restrict__ item, const float* __restrict__ w, int n_ui,
    int* __restrict__ cursor, int* __restrict__ comb, int n_ent) {
  int i = blockIdx.x * NT + threadIdx.x;
  if (i < n_kg) {
    int p = atomicAdd(&cursor[head[i]], 1);
    comb[p] = tail[i] | ((etype[i] - 1) << 20);
  }
  if (i < n_ui) {
    int p = atomicAdd(&cursor[n_ent + usr[i]], 1);
    int wq = (int)(w[i] * 16383.0f + 0.5f);
    if (wq > 16383) wq = 16383;
    comb[p] = (int)(((unsigned)item[i]) | (((unsigned)wq) << 18));
  }
}

// ---------------- degree-bucket sort of segments (type-pure, descending) ----------------
__device__ __forceinline__ int seg_bin(int deg, int i, int n_ent) {
  int d = deg < 63 ? deg : 63;
  return (i < n_ent ? 0 : 64) + 63 - d;
}

__global__ __launch_bounds__(NT) void k_bhist(const int* __restrict__ deg, int* __restrict__ bh,
                                              int n_ent, int n_seg) {
  __shared__ int lh[128];
  if (threadIdx.x < 128) lh[threadIdx.x] = 0;
  __syncthreads();
  for (int i = blockIdx.x * NT + threadIdx.x; i < n_seg; i += gridDim.x * NT)
    atomicAdd(&lh[seg_bin(deg[i], i, n_ent)], 1);
  __syncthreads();
  if (threadIdx.x < 128) atomicAdd(&bh[threadIdx.x], lh[threadIdx.x]);
}

__global__ __launch_bounds__(128) void k_bscan(int* __restrict__ bh) {
  __shared__ int sd[128];
  int t = threadIdx.x;
  int v = bh[t];
  sd[t] = v;
  __syncthreads();
  for (int off = 1; off < 128; off <<= 1) {
    int x = (t >= off) ? sd[t - off] : 0;
    __syncthreads();
    sd[t] += x;
    __syncthreads();
  }
  bh[t] = sd[t] - v;  // exclusive
}

__global__ __launch_bounds__(NT) void k_bscatter(const int* __restrict__ deg, int* __restrict__ bcur,
                                                 int* __restrict__ perm, int n_ent, int n_seg) {
  __shared__ int lh[128], lbase[128];
  if (threadIdx.x < 128) lh[threadIdx.x] = 0;
  __syncthreads();
  int start = blockIdx.x * NT + threadIdx.x, stride = gridDim.x * NT;
  for (int i = start; i < n_seg; i += stride)
    atomicAdd(&lh[seg_bin(deg[i], i, n_ent)], 1);
  __syncthreads();
  if (threadIdx.x < 128) {
    lbase[threadIdx.x] = atomicAdd(&bcur[threadIdx.x], lh[threadIdx.x]);
    lh[threadIdx.x] = 0;
  }
  __syncthreads();
  for (int i = start; i < n_seg; i += stride) {
    int b = seg_bin(deg[i], i, n_ent);
    int off = atomicAdd(&lh[b], 1);
    perm[lbase[b] + off] = i;
  }
}

// ---------------- MFMA GEMM: P-half(PC, fp8) = A @ W ----------------
__global__ __launch_bounds__(NT) void k_gemm(const char* __restrict__ PCin, const float* __restrict__ A32,
                                             const float* __restrict__ W, char* __restrict__ PCout, int M) {
  __shared__ u16 WT[128 * 136];  // W^T[n][k] bf16
  for (int i = threadIdx.x; i < 128 * 32; i += NT) {
    int n = i & 127, k4 = (i >> 7) << 2;
    u16x4 o = {f2bf(W[(k4 + 0) * 128 + n]), f2bf(W[(k4 + 1) * 128 + n]),
               f2bf(W[(k4 + 2) * 128 + n]), f2bf(W[(k4 + 3) * 128 + n])};
    *(u16x4*)&WT[n * 136 + k4] = o;
  }
  __syncthreads();
  int lane = threadIdx.x & 63;
  int l15 = lane & 15, l4 = lane >> 4;
  int wave = blockIdx.x * (NT / 64) + (threadIdx.x >> 6);
  int nw = gridDim.x * (NT / 64);
  int ntiles = (M + 15) >> 4;
  for (int tile = wave; tile < ntiles; tile += nw) {
    long row0 = (long)tile * 16;
    long myrow = row0 + l15;
    bool rowok = myrow < M;
    long ar = rowok ? myrow : (long)(M - 1);
    bf16x8 af[4];
    if (A32) {
      const float* arow = A32 + ar * 128;
#pragma unroll
      for (int kk = 0; kk < 4; ++kk) {
        const float* p = arow + kk * 32 + l4 * 8;
        float4 f0 = *(const float4*)p;
        float4 f1 = *(const float4*)(p + 4);
        u16x8 t = {f2bf(f0.x), f2bf(f0.y), f2bf(f0.z), f2bf(f0.w),
                   f2bf(f1.x), f2bf(f1.y), f2bf(f1.z), f2bf(f1.w)};
        af[kk] = *(bf16x8*)&t;
        if (rowok) *(u16x8*)(PCout + ar * PCS + 128 + kk * 64 + l4 * 16) = t;
      }
    } else {
      const char* arow = PCin + ar * PCS + 128;  // cur half (bf16)
#pragma unroll
      for (int kk = 0; kk < 4; ++kk) af[kk] = *(const bf16x8*)(arow + kk * 64 + l4 * 16);
    }
    f32x4 acc[8];
#pragma unroll
    for (int nt = 0; nt < 8; ++nt) acc[nt] = (f32x4){0.f, 0.f, 0.f, 0.f};
#pragma unroll
    for (int kk = 0; kk < 4; ++kk) {
#pragma unroll
      for (int nt = 0; nt < 8; ++nt) {
        bf16x8 bf = *(const bf16x8*)&WT[(nt * 16 + l15) * 136 + kk * 32 + l4 * 8];
        acc[nt] = __builtin_amdgcn_mfma_f32_16x16x32_bf16(af[kk], bf, acc[nt], 0, 0, 0);
      }
    }
#pragma unroll
    for (int nt = 0; nt < 8; ++nt) {
#pragma unroll
      for (int j = 0; j < 4; ++j) {
        long row = row0 + l4 * 4 + j;
        if (row < M) {
          float v = acc[nt][j];
          int pk = __builtin_amdgcn_cvt_pk_fp8_f32(v, v, 0, false);
          PCout[row * PCS + nt * 16 + l15] = (char)(pk & 0xFF);
        }
      }
    }
  }
}

// ---------------- fused segment aggregate (entity attention + user) ----------------
// One 16-lane unit per segment; 4 degree-matched segments per wave (perm).
// Batch-8 predicated structure: issue up to 8 gathers (no clamped dups),
// then consume 8 -- max MLP, zero waste at small degrees.
__global__ __launch_bounds__(NT) void k_agg(
    const char* __restrict__ PCc, const int* __restrict__ offs, const int* __restrict__ comb,
    const int* __restrict__ perm, const float* __restrict__ rel_emb,
    const float* __restrict__ base_e, const float* __restrict__ base_u,
    char* __restrict__ nextPC, float* __restrict__ res_e, float* __restrict__ res_u,
    int n_ent, int n_seg, int hop0) {
  __shared__ float rel[9 * 128];
  for (int i = threadIdx.x; i < 9 * 128; i += NT) rel[i] = rel_emb[i];
  __syncthreads();
  int lane = threadIdx.x & 63;
  int unit = lane >> 4;
  int cl = lane & 15;    // channel chunk (8 ch); head = cl>>3
  int chb = cl * 8;
  int vid = (((blockIdx.x * NT + threadIdx.x) >> 6) << 2) + unit;
  if (vid >= n_seg) return;
  int sseg = perm[vid];
  int beg = offs[sseg], end = offs[sseg + 1];

  if (sseg < n_ent) {
    // ---- entity attention path ----
    uint2 qv = *(const uint2*)(PCc + (size_t)sseg * PCS + (cl << 3));
    f32x2 q01 = __builtin_amdgcn_cvt_pk_f32_fp8((int)qv.x, false);
    f32x2 q23 = __builtin_amdgcn_cvt_pk_f32_fp8((int)qv.x, true);
    f32x2 q45 = __builtin_amdgcn_cvt_pk_f32_fp8((int)qv.y, false);
    f32x2 q67 = __builtin_amdgcn_cvt_pk_f32_fp8((int)qv.y, true);
    float q[8] = {q01[0] * 0.125f, q01[1] * 0.125f, q23[0] * 0.125f, q23[1] * 0.125f,
                  q45[0] * 0.125f, q45[1] * 0.125f, q67[0] * 0.125f, q67[1] * 0.125f};
    float s = 0.f;
    float a[8] = {0.f, 0.f, 0.f, 0.f, 0.f, 0.f, 0.f, 0.f};
    int i = beg;
    while (i < end) {
      int rem = end - i;  // >= 1
      unsigned te[8];
      uint2 Pv[8];
      u16x8 Cv[8];
#pragma unroll
      for (int k = 0; k < 8; ++k) {
        if (k < rem) {
          te[k] = (unsigned)comb[i + k];
          const char* rowp = PCc + (size_t)(te[k] & 0xFFFFF) * PCS;
          Pv[k] = *(const uint2*)(rowp + (cl << 3));
          Cv[k] = *(const u16x8*)(rowp + 128 + (cl << 4));
        }
      }
#pragma unroll
      for (int k = 0; k < 8; ++k) {
        if (k < rem) {
          const float* rp = &rel[(te[k] >> 20) * 128 + chb];
          float4 rA = *(const float4*)rp;
          float4 rB = *(const float4*)(rp + 4);
          f32x2 p01 = __builtin_amdgcn_cvt_pk_f32_fp8((int)Pv[k].x, false);
          f32x2 p23 = __builtin_amdgcn_cvt_pk_f32_fp8((int)Pv[k].x, true);
          f32x2 p45 = __builtin_amdgcn_cvt_pk_f32_fp8((int)Pv[k].y, false);
          f32x2 p67 = __builtin_amdgcn_cvt_pk_f32_fp8((int)Pv[k].y, true);
          float pp = q[0] * p01[0] * rA.x + q[1] * p01[1] * rA.y +
                     q[2] * p23[0] * rA.z + q[3] * p23[1] * rA.w +
                     q[4] * p45[0] * rB.x + q[5] * p45[1] * rB.y +
                     q[6] * p67[0] * rB.z + q[7] * p67[1] * rB.w;
          pp += __shfl_xor(pp, 1);
          pp += __shfl_xor(pp, 2);
          pp += __shfl_xor(pp, 4);
          float e = __expf(pp);
          s += e;
          a[0] = fmaf(bf2f(Cv[k][0]) * rA.x, e, a[0]);
          a[1] = fmaf(bf2f(Cv[k][1]) * rA.y, e, a[1]);
          a[2] = fmaf(bf2f(Cv[k][2]) * rA.z, e, a[2]);
          a[3] = fmaf(bf2f(Cv[k][3]) * rA.w, e, a[3]);
          a[4] = fmaf(bf2f(Cv[k][4]) * rB.x, e, a[4]);
          a[5] = fmaf(bf2f(Cv[k][5]) * rB.y, e, a[5]);
          a[6] = fmaf(bf2f(Cv[k][6]) * rB.z, e, a[6]);
          a[7] = fmaf(bf2f(Cv[k][7]) * rB.w, e, a[7]);
        }
      }
      i += 8;
    }
    float invs = 1.0f / fmaxf(s, 1e-16f);
    float gv[8];
    float nr = 0.f;
#pragma unroll
    for (int j = 0; j < 8; ++j) {
      gv[j] = a[j] * invs;
      nr += gv[j] * gv[j];
    }
    nr += __shfl_xor(nr, 1);
    nr += __shfl_xor(nr, 2);
    nr += __shfl_xor(nr, 4);
    nr += __shfl_xor(nr, 8);
    float inv = 1.0f / fmaxf(sqrtf(nr), 1e-12f);
#pragma unroll
    for (int j = 0; j < 8; ++j) gv[j] *= inv;
    if (hop0) {
      u16x8 o;
#pragma unroll
      for (int j = 0; j < 8; ++j) o[j] = f2bf(gv[j]);
      *(u16x8*)(nextPC + (size_t)sseg * PCS + 128 + (cl << 4)) = o;
    } else {
      u16x8 g0 = *(const u16x8*)(PCc + (size_t)sseg * PCS + 128 + (cl << 4));
      size_t o4 = (size_t)sseg * 128 + (size_t)chb;
      float4 b0 = *(const float4*)(base_e + o4);
      float4 b1 = *(const float4*)(base_e + o4 + 4);
      float4 w0 = {b0.x + bf2f(g0[0]) + gv[0], b0.y + bf2f(g0[1]) + gv[1],
                   b0.z + bf2f(g0[2]) + gv[2], b0.w + bf2f(g0[3]) + gv[3]};
      float4 w1 = {b1.x + bf2f(g0[4]) + gv[4], b1.y + bf2f(g0[5]) + gv[5],
                   b1.z + bf2f(g0[6]) + gv[6], b1.w + bf2f(g0[7]) + gv[7]};
      *(float4*)(res_e + o4) = w0;
      *(float4*)(res_e + o4 + 4) = w1;
    }
  } else {
    // ---- user aggregate path ----
    int u = sseg - n_ent;
    float a[8] = {0.f, 0.f, 0.f, 0.f, 0.f, 0.f, 0.f, 0.f};
    int i = beg;
    while (i < end) {
      int rem = end - i;
      unsigned iw[8];
      u16x8 Cv[8];
#pragma unroll
      for (int k = 0; k < 8; ++k) {
        if (k < rem) {
          iw[k] = (unsigned)comb[i + k];
          Cv[k] = *(const u16x8*)(PCc + (size_t)(iw[k] & 0x3FFFF) * PCS + 128 + (cl << 4));
        }
      }
#pragma unroll
      for (int k = 0; k < 8; ++k) {
        if (k < rem) {
          float ww = (float)(iw[k] >> 18) * (1.0f / 16383.0f);
#pragma unroll
          for (int j = 0; j < 8; ++j) a[j] = fmaf(bf2f(Cv[k][j]), ww, a[j]);
        }
      }
      i += 8;
    }
    float nr = 0.f;
#pragma unroll
    for (int j = 0; j < 8; ++j) nr += a[j] * a[j];
    nr += __shfl_xor(nr, 1);
    nr += __shfl_xor(nr, 2);
    nr += __shfl_xor(nr, 4);
    nr += __shfl_xor(nr, 8);
    float inv = 1.0f / fmaxf(sqrtf(nr), 1e-12f);
    size_t o = (size_t)u * 128 + (size_t)chb;
    const float* bp = hop0 ? (base_u + o) : (res_u + o);
    float4 r0 = *(const float4*)bp;
    float4 r1 = *(const float4*)(bp + 4);
    r0.x += a[0] * inv; r0.y += a[1] * inv; r0.z += a[2] * inv; r0.w += a[3] * inv;
    r1.x += a[4] * inv; r1.y += a[5] * inv; r1.z += a[6] * inv; r1.w += a[7] * inv;
    *(float4*)(res_u + o) = r0;
    *(float4*)(res_u + o + 4) = r1;
  }
}

// ---------------- host ----------------
extern "C" void kernel_launch(void* const* d_in, const int* in_sizes, int n_in,
                              void* d_out, int out_size, void* d_ws, size_t ws_size,
                              hipStream_t stream) {
  const float* user_emb = (const float*)d_in[0];
  const float* entity_emb = (const float*)d_in[1];
  const int* edge_index = (const int*)d_in[2];
  const int* edge_type = (const int*)d_in[3];
  const int* inter_edge = (const int*)d_in[4];
  const float* inter_w = (const float*)d_in[5];
  const float* rel_emb = (const float*)d_in[6];
  const float* W_Q = (const float*)d_in[7];
  float* out = (float*)d_out;

  int n_users = in_sizes[0] / 128;
  int n_ent = in_sizes[1] / 128;
  int e_kg = in_sizes[3];
  int e_ui = in_sizes[5];
  const int* head = edge_index;
  const int* tail = edge_index + e_kg;
  const int* iu = inter_edge;         // users
  const int* ii = inter_edge + e_ui;  // items

  int n_seg = n_ent + n_users;

  // workspace carve
  char* wp = (char*)d_ws;
  auto take = [&](size_t bytes) {
    char* p = wp;
    wp += (bytes + 255) & ~(size_t)255;
    return p;
  };
  char* PCa = take((size_t)n_ent * PCS);
  char* PCb = take((size_t)n_ent * PCS);
  int* deg = (int*)take((size_t)(n_seg + 1) * 4);
  int* offs = (int*)take((size_t)(n_seg + 1) * 4);
  int* cur = (int*)take((size_t)(n_seg + 1) * 4);
  int* comb = (int*)take((size_t)(e_kg + e_ui) * 4);
  int* perm = (int*)take((size_t)n_seg * 4);
  int* bh = (int*)take(512);
  int* aux = (int*)take(1024);
  (void)ws_size;
  (void)n_in;
  (void)out_size;

  // combined CSR build (shared by both hops)
  hipMemsetAsync(deg, 0, (size_t)(n_seg + 1) * 4, stream);
  hipMemsetAsync(bh, 0, 512, stream);
  int emax = e_kg > e_ui ? e_kg : e_ui;
  k_hist<<<(emax + NT - 1) / NT, NT, 0, stream>>>(head, e_kg, iu, e_ui, deg, n_ent);
  int nscan = n_seg + 1;
  int nb = (nscan + NT * 8 - 1) / (NT * 8);
  k_scan1<<<nb, NT, 0, stream>>>(deg, offs, aux, nscan);
  k_scan2<<<1, NT, 0, stream>>>(aux, nb);
  k_scan3<<<nb, NT, 0, stream>>>(offs, cur, aux, nscan);
  k_scatter<<<(emax + NT - 1) / NT, NT, 0, stream>>>(head, tail, edge_type, e_kg,
                                                     iu, ii, inter_w, e_ui, cur, comb, n_ent);
  // degree-bucket sort of segments
  k_bhist<<<128, NT, 0, stream>>>(deg, bh, n_ent, n_seg);
  k_bscan<<<1, 128, 0, stream>>>(bh);
  k_bscatter<<<128, NT, 0, stream>>>(deg, bh, perm, n_ent, n_seg);

  float* res_e = out;
  float* res_u = out + (size_t)n_ent * 128;
  int agg_blocks = (n_seg + 15) / 16;
  int gemm_blocks = (((n_ent + 15) >> 4) + 3) / 4;  // 1 tile per wave

  // hop 0: gemm reads fp32 entity_emb (fused cvt), agg writes nextPC only (entities)
  k_gemm<<<gemm_blocks, NT, 0, stream>>>(PCa, entity_emb, W_Q, PCa, n_ent);
  k_agg<<<agg_blocks, NT, 0, stream>>>(PCa, offs, comb, perm, rel_emb, entity_emb, user_emb,
                                       PCb, res_e, res_u, n_ent, n_seg, 1);
  // hop 1: gemm reads PCb cur-half, agg finalizes residuals
  k_gemm<<<gemm_blocks, NT, 0, stream>>>(PCb, nullptr, W_Q, PCb, n_ent);
  k_agg<<<agg_blocks, NT, 0, stream>>>(PCb, offs, comb, perm, rel_emb, entity_emb, nullptr,
                                       nullptr, res_e, res_u, n_ent, n_seg, 0);
}

// Round 9
// 574.285 us; speedup vs baseline: 1.1957x; 1.1957x over previous
//
#include <hip/hip_runtime.h>
#include <math.h>

#define NT 256
typedef unsigned short u16;
typedef __attribute__((ext_vector_type(8))) u16 u16x8;
typedef __attribute__((ext_vector_type(4))) u16 u16x4;
typedef __attribute__((ext_vector_type(8))) short bf16x8;
typedef __attribute__((ext_vector_type(4))) float f32x4;
typedef __attribute__((ext_vector_type(2))) float f32x2;

// PC row layout (stride 384 B): [0,128) fp8-e4m3 P (score side) | [128,384) bf16 cur (value side)
#define PCS 384

__device__ __forceinline__ float bf2f(u16 h) {
  union { unsigned u; float f; } v;
  v.u = ((unsigned)h) << 16;
  return v.f;
}
__device__ __forceinline__ u16 f2bf(float f) {
  union { float f; unsigned u; } v;
  v.f = f;
  unsigned r = v.u + 0x7FFFu + ((v.u >> 16) & 1u);
  return (u16)(r >> 16);
}

// ---------------- CSR build (combined entity+user) ----------------
__global__ __launch_bounds__(NT) void k_hist(const int* __restrict__ head, int n_kg,
                                             const int* __restrict__ usr, int n_ui,
                                             int* __restrict__ deg, int n_ent) {
  int i = blockIdx.x * NT + threadIdx.x;
  if (i < n_kg) atomicAdd(&deg[head[i]], 1);
  if (i < n_ui) atomicAdd(&deg[n_ent + usr[i]], 1);
}

__global__ __launch_bounds__(NT) void k_scan1(const int* __restrict__ in, int* __restrict__ out,
                                              int* __restrict__ aux, int n) {
  __shared__ int sd[NT];
  int t = threadIdx.x;
  int base = blockIdx.x * (NT * 8) + t * 8;
  int v[8], ex[8];
  int run = 0;
#pragma unroll
  for (int j = 0; j < 8; ++j) {
    v[j] = (base + j < n) ? in[base + j] : 0;
    ex[j] = run;
    run += v[j];
  }
  sd[t] = run;
  __syncthreads();
  for (int off = 1; off < NT; off <<= 1) {
    int x = (t >= off) ? sd[t - off] : 0;
    __syncthreads();
    sd[t] += x;
    __syncthreads();
  }
  int texcl = sd[t] - run;
#pragma unroll
  for (int j = 0; j < 8; ++j)
    if (base + j < n) out[base + j] = texcl + ex[j];
  if (t == NT - 1) aux[blockIdx.x] = sd[NT - 1];
}

__global__ __launch_bounds__(NT) void k_scan2(int* __restrict__ aux, int nb) {
  __shared__ int sd[NT];
  int t = threadIdx.x;
  int v = (t < nb) ? aux[t] : 0;
  sd[t] = v;
  __syncthreads();
  for (int off = 1; off < NT; off <<= 1) {
    int x = (t >= off) ? sd[t - off] : 0;
    __syncthreads();
    sd[t] += x;
    __syncthreads();
  }
  if (t < nb) aux[t] = sd[t] - v;  // exclusive
}

__global__ __launch_bounds__(NT) void k_scan3(int* __restrict__ out, int* __restrict__ cur,
                                              const int* __restrict__ aux, int n) {
  int base = blockIdx.x * (NT * 8) + threadIdx.x * 8;
  int add = aux[blockIdx.x];
#pragma unroll
  for (int j = 0; j < 8; ++j)
    if (base + j < n) {
      int v = out[base + j] + add;
      out[base + j] = v;
      cur[base + j] = v;
    }
}

__global__ __launch_bounds__(NT) void k_scatter(
    const int* __restrict__ head, const int* __restrict__ tail, const int* __restrict__ etype, int n_kg,
    const int* __restrict__ usr, const int* __restrict__ item, const float* __restrict__ w, int n_ui,
    int* __restrict__ cursor, int* __restrict__ comb, int n_ent) {
  int i = blockIdx.x * NT + threadIdx.x;
  if (i < n_kg) {
    int p = atomicAdd(&cursor[head[i]], 1);
    comb[p] = tail[i] | ((etype[i] - 1) << 20);
  }
  if (i < n_ui) {
    int p = atomicAdd(&cursor[n_ent + usr[i]], 1);
    int wq = (int)(w[i] * 16383.0f + 0.5f);
    if (wq > 16383) wq = 16383;
    comb[p] = (int)(((unsigned)item[i]) | (((unsigned)wq) << 18));
  }
}

// ---------------- MFMA GEMM: P-half(PC, fp8) = A @ W ----------------
// A32 != nullptr: hop0 -- A from fp32 entity_emb; also writes bf16 cur-half.
// Else A = cur-half (bf16) of PCin. Persistent-ish grid, tile loop.
__global__ __launch_bounds__(NT) void k_gemm(const char* __restrict__ PCin, const float* __restrict__ A32,
                                             const float* __restrict__ W, char* __restrict__ PCout, int M) {
  __shared__ u16 WT[128 * 136];  // W^T[n][k] bf16
  for (int i = threadIdx.x; i < 128 * 32; i += NT) {
    int n = i & 127, k4 = (i >> 7) << 2;
    u16x4 o = {f2bf(W[(k4 + 0) * 128 + n]), f2bf(W[(k4 + 1) * 128 + n]),
               f2bf(W[(k4 + 2) * 128 + n]), f2bf(W[(k4 + 3) * 128 + n])};
    *(u16x4*)&WT[n * 136 + k4] = o;
  }
  __syncthreads();
  int lane = threadIdx.x & 63;
  int l15 = lane & 15, l4 = lane >> 4;
  int wave = blockIdx.x * (NT / 64) + (threadIdx.x >> 6);
  int nw = gridDim.x * (NT / 64);
  int ntiles = (M + 15) >> 4;
  for (int tile = wave; tile < ntiles; tile += nw) {
    long row0 = (long)tile * 16;
    long myrow = row0 + l15;
    bool rowok = myrow < M;
    long ar = rowok ? myrow : (long)(M - 1);
    bf16x8 af[4];
    if (A32) {
      const float* arow = A32 + ar * 128;
#pragma unroll
      for (int kk = 0; kk < 4; ++kk) {
        const float* p = arow + kk * 32 + l4 * 8;
        float4 f0 = *(const float4*)p;
        float4 f1 = *(const float4*)(p + 4);
        u16x8 t = {f2bf(f0.x), f2bf(f0.y), f2bf(f0.z), f2bf(f0.w),
                   f2bf(f1.x), f2bf(f1.y), f2bf(f1.z), f2bf(f1.w)};
        af[kk] = *(bf16x8*)&t;
        if (rowok) *(u16x8*)(PCout + ar * PCS + 128 + kk * 64 + l4 * 16) = t;
      }
    } else {
      const char* arow = PCin + ar * PCS + 128;  // cur half (bf16)
#pragma unroll
      for (int kk = 0; kk < 4; ++kk) af[kk] = *(const bf16x8*)(arow + kk * 64 + l4 * 16);
    }
    f32x4 acc[8];
#pragma unroll
    for (int nt = 0; nt < 8; ++nt) acc[nt] = (f32x4){0.f, 0.f, 0.f, 0.f};
#pragma unroll
    for (int kk = 0; kk < 4; ++kk) {
#pragma unroll
      for (int nt = 0; nt < 8; ++nt) {
        bf16x8 bf = *(const bf16x8*)&WT[(nt * 16 + l15) * 136 + kk * 32 + l4 * 8];
        acc[nt] = __builtin_amdgcn_mfma_f32_16x16x32_bf16(af[kk], bf, acc[nt], 0, 0, 0);
      }
    }
#pragma unroll
    for (int nt = 0; nt < 8; ++nt) {
#pragma unroll
      for (int j = 0; j < 4; ++j) {
        long row = row0 + l4 * 4 + j;
        if (row < M) {
          float v = acc[nt][j];
          int pk = __builtin_amdgcn_cvt_pk_fp8_f32(v, v, 0, false);
          PCout[row * PCS + nt * 16 + l15] = (char)(pk & 0xFF);
        }
      }
    }
  }
}

// ---------------- fused segment aggregate (entity attention + user) ----------------
// One 16-lane unit per segment; 4 segments per wave, NATURAL order (preserves
// graph/write locality -- measured better than degree-sorted). r5-proven
// dist-1 rotating prefetch; fp8 score-side gathers, bf16 value gathers.
__global__ __launch_bounds__(NT) void k_agg(
    const char* __restrict__ PCc, const int* __restrict__ offs, const int* __restrict__ comb,
    const float* __restrict__ rel_emb, const float* __restrict__ base_e,
    const float* __restrict__ base_u, char* __restrict__ nextPC,
    float* __restrict__ res_e, float* __restrict__ res_u, int n_ent, int n_seg, int hop0) {
  __shared__ float rel[9 * 128];
  for (int i = threadIdx.x; i < 9 * 128; i += NT) rel[i] = rel_emb[i];
  __syncthreads();
  int lane = threadIdx.x & 63;
  int unit = lane >> 4;
  int cl = lane & 15;    // channel chunk (8 ch); head = cl>>3
  int chb = cl * 8;
  int sseg = (((blockIdx.x * NT + threadIdx.x) >> 6) << 2) + unit;
  if (sseg >= n_seg) return;
  int beg = offs[sseg], end = offs[sseg + 1];
  int cnt = end - beg;

  if (sseg < n_ent) {
    // ---- entity attention path ----
    uint2 qv = *(const uint2*)(PCc + (size_t)sseg * PCS + (cl << 3));
    f32x2 q01 = __builtin_amdgcn_cvt_pk_f32_fp8((int)qv.x, false);
    f32x2 q23 = __builtin_amdgcn_cvt_pk_f32_fp8((int)qv.x, true);
    f32x2 q45 = __builtin_amdgcn_cvt_pk_f32_fp8((int)qv.y, false);
    f32x2 q67 = __builtin_amdgcn_cvt_pk_f32_fp8((int)qv.y, true);
    float q[8] = {q01[0] * 0.125f, q01[1] * 0.125f, q23[0] * 0.125f, q23[1] * 0.125f,
                  q45[0] * 0.125f, q45[1] * 0.125f, q67[0] * 0.125f, q67[1] * 0.125f};
    float s = 0.f;
    float a[8] = {0.f, 0.f, 0.f, 0.f, 0.f, 0.f, 0.f, 0.f};
    int idx = beg;
    bool act = idx < end;
    unsigned te = act ? (unsigned)comb[idx] : 0u;
    const char* rowp = PCc + (size_t)(te & 0xFFFFF) * PCS;
    uint2 P0 = act ? *(const uint2*)(rowp + (cl << 3)) : (uint2){0, 0};
    u16x8 C0 = act ? *(const u16x8*)(rowp + 128 + (cl << 4)) : (u16x8){};
    while (act) {
      int nidx = idx + 1;
      bool nact = nidx < end;
      unsigned nte = nact ? (unsigned)comb[nidx] : 0u;
      const char* nrp = PCc + (size_t)(nte & 0xFFFFF) * PCS;
      uint2 nP = *(const uint2*)(nrp + (cl << 3));
      u16x8 nC = *(const u16x8*)(nrp + 128 + (cl << 4));
      // process current
      const float* rp = &rel[(te >> 20) * 128 + chb];
      float4 rA = *(const float4*)rp;
      float4 rB = *(const float4*)(rp + 4);
      f32x2 p01 = __builtin_amdgcn_cvt_pk_f32_fp8((int)P0.x, false);
      f32x2 p23 = __builtin_amdgcn_cvt_pk_f32_fp8((int)P0.x, true);
      f32x2 p45 = __builtin_amdgcn_cvt_pk_f32_fp8((int)P0.y, false);
      f32x2 p67 = __builtin_amdgcn_cvt_pk_f32_fp8((int)P0.y, true);
      float pp = q[0] * p01[0] * rA.x + q[1] * p01[1] * rA.y +
                 q[2] * p23[0] * rA.z + q[3] * p23[1] * rA.w +
                 q[4] * p45[0] * rB.x + q[5] * p45[1] * rB.y +
                 q[6] * p67[0] * rB.z + q[7] * p67[1] * rB.w;
      pp += __shfl_xor(pp, 1);
      pp += __shfl_xor(pp, 2);
      pp += __shfl_xor(pp, 4);  // per-head score on its own lanes
      float e = __expf(pp);
      s += e;
      a[0] = fmaf(bf2f(C0[0]) * rA.x, e, a[0]);
      a[1] = fmaf(bf2f(C0[1]) * rA.y, e, a[1]);
      a[2] = fmaf(bf2f(C0[2]) * rA.z, e, a[2]);
      a[3] = fmaf(bf2f(C0[3]) * rA.w, e, a[3]);
      a[4] = fmaf(bf2f(C0[4]) * rB.x, e, a[4]);
      a[5] = fmaf(bf2f(C0[5]) * rB.y, e, a[5]);
      a[6] = fmaf(bf2f(C0[6]) * rB.z, e, a[6]);
      a[7] = fmaf(bf2f(C0[7]) * rB.w, e, a[7]);
      P0 = nP;
      C0 = nC;
      te = nte;
      idx = nidx;
      act = nact;
    }
    float invs = 1.0f / fmaxf(s, 1e-16f);
    float gv[8];
    float nr = 0.f;
#pragma unroll
    for (int j = 0; j < 8; ++j) {
      gv[j] = a[j] * invs;
      nr += gv[j] * gv[j];
    }
    nr += __shfl_xor(nr, 1);
    nr += __shfl_xor(nr, 2);
    nr += __shfl_xor(nr, 4);
    nr += __shfl_xor(nr, 8);  // norm spans both heads
    float inv = 1.0f / fmaxf(sqrtf(nr), 1e-12f);
#pragma unroll
    for (int j = 0; j < 8; ++j) gv[j] *= inv;
    if (hop0) {
      u16x8 o;
#pragma unroll
      for (int j = 0; j < 8; ++j) o[j] = f2bf(gv[j]);
      *(u16x8*)(nextPC + (size_t)sseg * PCS + 128 + (cl << 4)) = o;
    } else {
      u16x8 g0 = *(const u16x8*)(PCc + (size_t)sseg * PCS + 128 + (cl << 4));
      size_t o4 = (size_t)sseg * 128 + (size_t)chb;
      float4 b0 = *(const float4*)(base_e + o4);
      float4 b1 = *(const float4*)(base_e + o4 + 4);
      float4 w0 = {b0.x + bf2f(g0[0]) + gv[0], b0.y + bf2f(g0[1]) + gv[1],
                   b0.z + bf2f(g0[2]) + gv[2], b0.w + bf2f(g0[3]) + gv[3]};
      float4 w1 = {b1.x + bf2f(g0[4]) + gv[4], b1.y + bf2f(g0[5]) + gv[5],
                   b1.z + bf2f(g0[6]) + gv[6], b1.w + bf2f(g0[7]) + gv[7]};
      *(float4*)(res_e + o4) = w0;
      *(float4*)(res_e + o4 + 4) = w1;
    }
  } else {
    // ---- user aggregate path ----
    int u = sseg - n_ent;
    float a[8] = {0.f, 0.f, 0.f, 0.f, 0.f, 0.f, 0.f, 0.f};
    int idx = beg;
    bool act = idx < end;
    unsigned iw = act ? (unsigned)comb[idx] : 0u;
    u16x8 C0 = act ? *(const u16x8*)(PCc + (size_t)(iw & 0x3FFFF) * PCS + 128 + (cl << 4))
                   : (u16x8){};
    while (act) {
      int nidx = idx + 1;
      bool nact = nidx < end;
      unsigned niw = nact ? (unsigned)comb[nidx] : 0u;
      u16x8 nC = *(const u16x8*)(PCc + (size_t)(niw & 0x3FFFF) * PCS + 128 + (cl << 4));
      float ww = (float)(iw >> 18) * (1.0f / 16383.0f);
#pragma unroll
      for (int j = 0; j < 8; ++j) a[j] = fmaf(bf2f(C0[j]), ww, a[j]);
      C0 = nC;
      iw = niw;
      idx = nidx;
      act = nact;
    }
    float nr = 0.f;
#pragma unroll
    for (int j = 0; j < 8; ++j) nr += a[j] * a[j];
    nr += __shfl_xor(nr, 1);
    nr += __shfl_xor(nr, 2);
    nr += __shfl_xor(nr, 4);
    nr += __shfl_xor(nr, 8);
    float inv = 1.0f / fmaxf(sqrtf(nr), 1e-12f);
    size_t o = (size_t)u * 128 + (size_t)chb;
    const float* bp = hop0 ? (base_u + o) : (res_u + o);
    float4 r0 = *(const float4*)bp;
    float4 r1 = *(const float4*)(bp + 4);
    r0.x += a[0] * inv; r0.y += a[1] * inv; r0.z += a[2] * inv; r0.w += a[3] * inv;
    r1.x += a[4] * inv; r1.y += a[5] * inv; r1.z += a[6] * inv; r1.w += a[7] * inv;
    *(float4*)(res_u + o) = r0;
    *(float4*)(res_u + o + 4) = r1;
  }
}

// ---------------- host ----------------
extern "C" void kernel_launch(void* const* d_in, const int* in_sizes, int n_in,
                              void* d_out, int out_size, void* d_ws, size_t ws_size,
                              hipStream_t stream) {
  const float* user_emb = (const float*)d_in[0];
  const float* entity_emb = (const float*)d_in[1];
  const int* edge_index = (const int*)d_in[2];
  const int* edge_type = (const int*)d_in[3];
  const int* inter_edge = (const int*)d_in[4];
  const float* inter_w = (const float*)d_in[5];
  const float* rel_emb = (const float*)d_in[6];
  const float* W_Q = (const float*)d_in[7];
  float* out = (float*)d_out;

  int n_users = in_sizes[0] / 128;
  int n_ent = in_sizes[1] / 128;
  int e_kg = in_sizes[3];
  int e_ui = in_sizes[5];
  const int* head = edge_index;
  const int* tail = edge_index + e_kg;
  const int* iu = inter_edge;         // users
  const int* ii = inter_edge + e_ui;  // items

  int n_seg = n_ent + n_users;

  // workspace carve
  char* wp = (char*)d_ws;
  auto take = [&](size_t bytes) {
    char* p = wp;
    wp += (bytes + 255) & ~(size_t)255;
    return p;
  };
  char* PCa = take((size_t)n_ent * PCS);
  char* PCb = take((size_t)n_ent * PCS);
  int* deg = (int*)take((size_t)(n_seg + 1) * 4);
  int* offs = (int*)take((size_t)(n_seg + 1) * 4);
  int* cur = (int*)take((size_t)(n_seg + 1) * 4);
  int* comb = (int*)take((size_t)(e_kg + e_ui) * 4);
  int* aux = (int*)take(1024);
  (void)ws_size;
  (void)n_in;
  (void)out_size;

  // combined CSR build (shared by both hops)
  hipMemsetAsync(deg, 0, (size_t)(n_seg + 1) * 4, stream);
  int emax = e_kg > e_ui ? e_kg : e_ui;
  k_hist<<<(emax + NT - 1) / NT, NT, 0, stream>>>(head, e_kg, iu, e_ui, deg, n_ent);
  int nscan = n_seg + 1;
  int nb = (nscan + NT * 8 - 1) / (NT * 8);
  k_scan1<<<nb, NT, 0, stream>>>(deg, offs, aux, nscan);
  k_scan2<<<1, NT, 0, stream>>>(aux, nb);
  k_scan3<<<nb, NT, 0, stream>>>(offs, cur, aux, nscan);
  k_scatter<<<(emax + NT - 1) / NT, NT, 0, stream>>>(head, tail, edge_type, e_kg,
                                                     iu, ii, inter_w, e_ui, cur, comb, n_ent);

  float* res_e = out;
  float* res_u = out + (size_t)n_ent * 128;
  int agg_blocks = (n_seg + 15) / 16;

  // hop 0: gemm reads fp32 entity_emb (fused cvt), agg writes nextPC only (entities)
  k_gemm<<<1024, NT, 0, stream>>>(PCa, entity_emb, W_Q, PCa, n_ent);
  k_agg<<<agg_blocks, NT, 0, stream>>>(PCa, offs, comb, rel_emb, entity_emb, user_emb,
                                       PCb, res_e, res_u, n_ent, n_seg, 1);
  // hop 1: gemm reads PCb cur-half, agg finalizes residuals
  k_gemm<<<1024, NT, 0, stream>>>(PCb, nullptr, W_Q, PCb, n_ent);
  k_agg<<<agg_blocks, NT, 0, stream>>>(PCb, offs, comb, rel_emb, entity_emb, nullptr,
                                       nullptr, res_e, res_u, n_ent, n_seg, 0);
}

// Round 10
// 458.079 us; speedup vs baseline: 1.4990x; 1.2537x over previous
//
#include <hip/hip_runtime.h>
#include <math.h>

#define NT 256
#define SH 9          // segments per bucket = 512
typedef unsigned short u16;
typedef __attribute__((ext_vector_type(8))) u16 u16x8;
typedef __attribute__((ext_vector_type(4))) u16 u16x4;
typedef __attribute__((ext_vector_type(8))) short bf16x8;
typedef __attribute__((ext_vector_type(4))) float f32x4;
typedef __attribute__((ext_vector_type(2))) float f32x2;

// PC row layout (stride 384 B): [0,128) fp8-e4m3 P (score side) | [128,384) bf16 cur (value side)
#define PCS 384

__device__ __forceinline__ float bf2f(u16 h) {
  union { unsigned u; float f; } v;
  v.u = ((unsigned)h) << 16;
  return v.f;
}
__device__ __forceinline__ u16 f2bf(float f) {
  union { float f; unsigned u; } v;
  v.f = f;
  unsigned r = v.u + 0x7FFFu + ((v.u >> 16) & 1u);
  return (u16)(r >> 16);
}

// ---------------- bucketed CSR build ----------------
// Pass A: bucket histogram -- LDS only, no per-edge global atomics.
__global__ __launch_bounds__(NT) void k_phist(const int* __restrict__ head, int n_kg,
                                              const int* __restrict__ usr, int n_ui,
                                              int* __restrict__ bh, int n_ent, int nbk) {
  __shared__ int lh[1024];
  for (int i = threadIdx.x; i < nbk; i += NT) lh[i] = 0;
  __syncthreads();
  int emax = n_kg > n_ui ? n_kg : n_ui;
  int per = (emax + gridDim.x - 1) / gridDim.x;
  int lo = blockIdx.x * per;
  int hi = lo + per < emax ? lo + per : emax;
  for (int i = lo + threadIdx.x; i < hi; i += NT) {
    if (i < n_kg) atomicAdd(&lh[head[i] >> SH], 1);
    if (i < n_ui) atomicAdd(&lh[(n_ent + usr[i]) >> SH], 1);
  }
  __syncthreads();
  for (int b = threadIdx.x; b < nbk; b += NT)
    if (lh[b]) atomicAdd(&bh[b], lh[b]);
}

// Pass B: exclusive scan of bucket counts (<=1024 bins), writes bbase and bcur.
__global__ __launch_bounds__(NT) void k_bscan(const int* __restrict__ bh, int* __restrict__ bbase,
                                              int* __restrict__ bcur, int nbk) {
  __shared__ int sd[NT];
  int t = threadIdx.x;
  int v[4], l[4];
  int run = 0;
#pragma unroll
  for (int j = 0; j < 4; ++j) {
    int idx = t * 4 + j;
    v[j] = (idx < nbk) ? bh[idx] : 0;
    l[j] = run;
    run += v[j];
  }
  sd[t] = run;
  __syncthreads();
  for (int off = 1; off < NT; off <<= 1) {
    int x = (t >= off) ? sd[t - off] : 0;
    __syncthreads();
    sd[t] += x;
    __syncthreads();
  }
  int base = sd[t] - run;
#pragma unroll
  for (int j = 0; j < 4; ++j) {
    int idx = t * 4 + j;
    if (idx < nbk) {
      bbase[idx] = base + l[j];
      bcur[idx] = base + l[j];
    }
  }
}

// Pass C: chunked scatter into bucket-ordered ebuf. Each block reserves one
// chunk per bucket (1 atomic) and writes its members contiguously -> dense
// 8B writes, no cross-XCD line bouncing.
__global__ __launch_bounds__(NT) void k_pscatter(
    const int* __restrict__ head, const int* __restrict__ tail, const int* __restrict__ etype, int n_kg,
    const int* __restrict__ usr, const int* __restrict__ item, const float* __restrict__ w, int n_ui,
    int* __restrict__ bcur, uint2* __restrict__ ebuf, int n_ent, int nbk) {
  __shared__ int lh[1024], lbase[1024];
  for (int i = threadIdx.x; i < nbk; i += NT) lh[i] = 0;
  __syncthreads();
  int emax = n_kg > n_ui ? n_kg : n_ui;
  int per = (emax + gridDim.x - 1) / gridDim.x;
  int lo = blockIdx.x * per;
  int hi = lo + per < emax ? lo + per : emax;
  // phase 1: count this block's members per bucket
  for (int i = lo + threadIdx.x; i < hi; i += NT) {
    if (i < n_kg) atomicAdd(&lh[head[i] >> SH], 1);
    if (i < n_ui) atomicAdd(&lh[(n_ent + usr[i]) >> SH], 1);
  }
  __syncthreads();
  for (int b = threadIdx.x; b < nbk; b += NT) {
    lbase[b] = lh[b] ? atomicAdd(&bcur[b], lh[b]) : 0;
    lh[b] = 0;
  }
  __syncthreads();
  // phase 2: place
  for (int i = lo + threadIdx.x; i < hi; i += NT) {
    if (i < n_kg) {
      int key = head[i];
      int b = key >> SH;
      int slot = lbase[b] + atomicAdd(&lh[b], 1);
      ebuf[slot] = (uint2){(unsigned)key, (unsigned)(tail[i] | ((etype[i] - 1) << 20))};
    }
    if (i < n_ui) {
      int key = n_ent + usr[i];
      int b = key >> SH;
      int wq = (int)(w[i] * 16383.0f + 0.5f);
      if (wq > 16383) wq = 16383;
      int slot = lbase[b] + atomicAdd(&lh[b], 1);
      ebuf[slot] = (uint2){(unsigned)key, ((unsigned)item[i]) | (((unsigned)wq) << 18)};
    }
  }
}

// Pass D: one block per bucket. Count per segment (LDS), scan, write offs for
// the bucket's segments, place payloads into comb via LDS cursors. All comb
// writes for this bucket come from ONE CU -> each line written back once.
__global__ __launch_bounds__(NT) void k_fscatter(const uint2* __restrict__ ebuf,
                                                 const int* __restrict__ bbase,
                                                 const int* __restrict__ bcur,
                                                 int* __restrict__ offs, int* __restrict__ comb,
                                                 int n_seg, int nbk) {
  __shared__ int cnt[512];
  __shared__ int excl[512];
  __shared__ int sd[NT];
  int b = blockIdx.x;
  int t = threadIdx.x;
  int seg0 = b << SH;
  int e0 = bbase[b], e1 = bcur[b];
  cnt[t] = 0;
  cnt[t + 256] = 0;
  __syncthreads();
  for (int i = e0 + t; i < e1; i += NT) atomicAdd(&cnt[(int)ebuf[i].x - seg0], 1);
  __syncthreads();
  // exclusive scan of cnt[512] (2 bins per thread)
  int v0 = cnt[2 * t], v1 = cnt[2 * t + 1];
  int pair = v0 + v1;
  sd[t] = pair;
  __syncthreads();
  for (int off = 1; off < NT; off <<= 1) {
    int x = (t >= off) ? sd[t - off] : 0;
    __syncthreads();
    sd[t] += x;
    __syncthreads();
  }
  int before = sd[t] - pair;
  excl[2 * t] = before;
  excl[2 * t + 1] = before + v0;
  __syncthreads();
  // write offs for this bucket's segments
#pragma unroll
  for (int j = 0; j < 2; ++j) {
    int s = t + j * 256;
    int gs = seg0 + s;
    if (gs < n_seg) offs[gs] = e0 + excl[s];
  }
  if (b == nbk - 1 && t == 0) offs[n_seg] = e1;
  __syncthreads();
  // place (reuse cnt as cursors)
  cnt[2 * t] = 0;
  cnt[2 * t + 1] = 0;
  __syncthreads();
  for (int i = e0 + t; i < e1; i += NT) {
    uint2 v = ebuf[i];
    int s = (int)v.x - seg0;
    int p = atomicAdd(&cnt[s], 1);
    comb[e0 + excl[s] + p] = (int)v.y;
  }
}

// ---------------- MFMA GEMM: P-half(PC, fp8) = A @ W ----------------
__global__ __launch_bounds__(NT) void k_gemm(const char* __restrict__ PCin, const float* __restrict__ A32,
                                             const float* __restrict__ W, char* __restrict__ PCout, int M) {
  __shared__ u16 WT[128 * 136];  // W^T[n][k] bf16
  for (int i = threadIdx.x; i < 128 * 32; i += NT) {
    int n = i & 127, k4 = (i >> 7) << 2;
    u16x4 o = {f2bf(W[(k4 + 0) * 128 + n]), f2bf(W[(k4 + 1) * 128 + n]),
               f2bf(W[(k4 + 2) * 128 + n]), f2bf(W[(k4 + 3) * 128 + n])};
    *(u16x4*)&WT[n * 136 + k4] = o;
  }
  __syncthreads();
  int lane = threadIdx.x & 63;
  int l15 = lane & 15, l4 = lane >> 4;
  int wave = blockIdx.x * (NT / 64) + (threadIdx.x >> 6);
  int nw = gridDim.x * (NT / 64);
  int ntiles = (M + 15) >> 4;
  for (int tile = wave; tile < ntiles; tile += nw) {
    long row0 = (long)tile * 16;
    long myrow = row0 + l15;
    bool rowok = myrow < M;
    long ar = rowok ? myrow : (long)(M - 1);
    bf16x8 af[4];
    if (A32) {
      const float* arow = A32 + ar * 128;
#pragma unroll
      for (int kk = 0; kk < 4; ++kk) {
        const float* p = arow + kk * 32 + l4 * 8;
        float4 f0 = *(const float4*)p;
        float4 f1 = *(const float4*)(p + 4);
        u16x8 t = {f2bf(f0.x), f2bf(f0.y), f2bf(f0.z), f2bf(f0.w),
                   f2bf(f1.x), f2bf(f1.y), f2bf(f1.z), f2bf(f1.w)};
        af[kk] = *(bf16x8*)&t;
        if (rowok) *(u16x8*)(PCout + ar * PCS + 128 + kk * 64 + l4 * 16) = t;
      }
    } else {
      const char* arow = PCin + ar * PCS + 128;  // cur half (bf16)
#pragma unroll
      for (int kk = 0; kk < 4; ++kk) af[kk] = *(const bf16x8*)(arow + kk * 64 + l4 * 16);
    }
    f32x4 acc[8];
#pragma unroll
    for (int nt = 0; nt < 8; ++nt) acc[nt] = (f32x4){0.f, 0.f, 0.f, 0.f};
#pragma unroll
    for (int kk = 0; kk < 4; ++kk) {
#pragma unroll
      for (int nt = 0; nt < 8; ++nt) {
        bf16x8 bf = *(const bf16x8*)&WT[(nt * 16 + l15) * 136 + kk * 32 + l4 * 8];
        acc[nt] = __builtin_amdgcn_mfma_f32_16x16x32_bf16(af[kk], bf, acc[nt], 0, 0, 0);
      }
    }
#pragma unroll
    for (int nt = 0; nt < 8; ++nt) {
#pragma unroll
      for (int j = 0; j < 4; ++j) {
        long row = row0 + l4 * 4 + j;
        if (row < M) {
          float v = acc[nt][j];
          int pk = __builtin_amdgcn_cvt_pk_fp8_f32(v, v, 0, false);
          PCout[row * PCS + nt * 16 + l15] = (char)(pk & 0xFF);
        }
      }
    }
  }
}

// ---------------- fused segment aggregate (entity attention + user) ----------------
// One 16-lane unit per segment; 4 segments per wave, natural order.
// dist-1 rotating prefetch; fp8 score-side gathers, bf16 value gathers.
__global__ __launch_bounds__(NT) void k_agg(
    const char* __restrict__ PCc, const int* __restrict__ offs, const int* __restrict__ comb,
    const float* __restrict__ rel_emb, const float* __restrict__ base_e,
    const float* __restrict__ base_u, char* __restrict__ nextPC,
    float* __restrict__ res_e, float* __restrict__ res_u, int n_ent, int n_seg, int hop0) {
  __shared__ float rel[9 * 128];
  for (int i = threadIdx.x; i < 9 * 128; i += NT) rel[i] = rel_emb[i];
  __syncthreads();
  int lane = threadIdx.x & 63;
  int unit = lane >> 4;
  int cl = lane & 15;    // channel chunk (8 ch); head = cl>>3
  int chb = cl * 8;
  int sseg = (((blockIdx.x * NT + threadIdx.x) >> 6) << 2) + unit;
  if (sseg >= n_seg) return;
  int beg = offs[sseg], end = offs[sseg + 1];

  if (sseg < n_ent) {
    // ---- entity attention path ----
    uint2 qv = *(const uint2*)(PCc + (size_t)sseg * PCS + (cl << 3));
    f32x2 q01 = __builtin_amdgcn_cvt_pk_f32_fp8((int)qv.x, false);
    f32x2 q23 = __builtin_amdgcn_cvt_pk_f32_fp8((int)qv.x, true);
    f32x2 q45 = __builtin_amdgcn_cvt_pk_f32_fp8((int)qv.y, false);
    f32x2 q67 = __builtin_amdgcn_cvt_pk_f32_fp8((int)qv.y, true);
    float q[8] = {q01[0] * 0.125f, q01[1] * 0.125f, q23[0] * 0.125f, q23[1] * 0.125f,
                  q45[0] * 0.125f, q45[1] * 0.125f, q67[0] * 0.125f, q67[1] * 0.125f};
    float s = 0.f;
    float a[8] = {0.f, 0.f, 0.f, 0.f, 0.f, 0.f, 0.f, 0.f};
    int idx = beg;
    bool act = idx < end;
    unsigned te = act ? (unsigned)comb[idx] : 0u;
    const char* rowp = PCc + (size_t)(te & 0xFFFFF) * PCS;
    uint2 P0 = act ? *(const uint2*)(rowp + (cl << 3)) : (uint2){0, 0};
    u16x8 C0 = act ? *(const u16x8*)(rowp + 128 + (cl << 4)) : (u16x8){};
    while (act) {
      int nidx = idx + 1;
      bool nact = nidx < end;
      unsigned nte = nact ? (unsigned)comb[nidx] : 0u;
      const char* nrp = PCc + (size_t)(nte & 0xFFFFF) * PCS;
      uint2 nP = *(const uint2*)(nrp + (cl << 3));
      u16x8 nC = *(const u16x8*)(nrp + 128 + (cl << 4));
      const float* rp = &rel[(te >> 20) * 128 + chb];
      float4 rA = *(const float4*)rp;
      float4 rB = *(const float4*)(rp + 4);
      f32x2 p01 = __builtin_amdgcn_cvt_pk_f32_fp8((int)P0.x, false);
      f32x2 p23 = __builtin_amdgcn_cvt_pk_f32_fp8((int)P0.x, true);
      f32x2 p45 = __builtin_amdgcn_cvt_pk_f32_fp8((int)P0.y, false);
      f32x2 p67 = __builtin_amdgcn_cvt_pk_f32_fp8((int)P0.y, true);
      float pp = q[0] * p01[0] * rA.x + q[1] * p01[1] * rA.y +
                 q[2] * p23[0] * rA.z + q[3] * p23[1] * rA.w +
                 q[4] * p45[0] * rB.x + q[5] * p45[1] * rB.y +
                 q[6] * p67[0] * rB.z + q[7] * p67[1] * rB.w;
      pp += __shfl_xor(pp, 1);
      pp += __shfl_xor(pp, 2);
      pp += __shfl_xor(pp, 4);  // per-head score on its own lanes
      float e = __expf(pp);
      s += e;
      a[0] = fmaf(bf2f(C0[0]) * rA.x, e, a[0]);
      a[1] = fmaf(bf2f(C0[1]) * rA.y, e, a[1]);
      a[2] = fmaf(bf2f(C0[2]) * rA.z, e, a[2]);
      a[3] = fmaf(bf2f(C0[3]) * rA.w, e, a[3]);
      a[4] = fmaf(bf2f(C0[4]) * rB.x, e, a[4]);
      a[5] = fmaf(bf2f(C0[5]) * rB.y, e, a[5]);
      a[6] = fmaf(bf2f(C0[6]) * rB.z, e, a[6]);
      a[7] = fmaf(bf2f(C0[7]) * rB.w, e, a[7]);
      P0 = nP;
      C0 = nC;
      te = nte;
      idx = nidx;
      act = nact;
    }
    float invs = 1.0f / fmaxf(s, 1e-16f);
    float gv[8];
    float nr = 0.f;
#pragma unroll
    for (int j = 0; j < 8; ++j) {
      gv[j] = a[j] * invs;
      nr += gv[j] * gv[j];
    }
    nr += __shfl_xor(nr, 1);
    nr += __shfl_xor(nr, 2);
    nr += __shfl_xor(nr, 4);
    nr += __shfl_xor(nr, 8);  // norm spans both heads
    float inv = 1.0f / fmaxf(sqrtf(nr), 1e-12f);
#pragma unroll
    for (int j = 0; j < 8; ++j) gv[j] *= inv;
    if (hop0) {
      u16x8 o;
#pragma unroll
      for (int j = 0; j < 8; ++j) o[j] = f2bf(gv[j]);
      *(u16x8*)(nextPC + (size_t)sseg * PCS + 128 + (cl << 4)) = o;
    } else {
      u16x8 g0 = *(const u16x8*)(PCc + (size_t)sseg * PCS + 128 + (cl << 4));
      size_t o4 = (size_t)sseg * 128 + (size_t)chb;
      float4 b0 = *(const float4*)(base_e + o4);
      float4 b1 = *(const float4*)(base_e + o4 + 4);
      float4 w0 = {b0.x + bf2f(g0[0]) + gv[0], b0.y + bf2f(g0[1]) + gv[1],
                   b0.z + bf2f(g0[2]) + gv[2], b0.w + bf2f(g0[3]) + gv[3]};
      float4 w1 = {b1.x + bf2f(g0[4]) + gv[4], b1.y + bf2f(g0[5]) + gv[5],
                   b1.z + bf2f(g0[6]) + gv[6], b1.w + bf2f(g0[7]) + gv[7]};
      *(float4*)(res_e + o4) = w0;
      *(float4*)(res_e + o4 + 4) = w1;
    }
  } else {
    // ---- user aggregate path ----
    int u = sseg - n_ent;
    float a[8] = {0.f, 0.f, 0.f, 0.f, 0.f, 0.f, 0.f, 0.f};
    int idx = beg;
    bool act = idx < end;
    unsigned iw = act ? (unsigned)comb[idx] : 0u;
    u16x8 C0 = act ? *(const u16x8*)(PCc + (size_t)(iw & 0x3FFFF) * PCS + 128 + (cl << 4))
                   : (u16x8){};
    while (act) {
      int nidx = idx + 1;
      bool nact = nidx < end;
      unsigned niw = nact ? (unsigned)comb[nidx] : 0u;
      u16x8 nC = *(const u16x8*)(PCc + (size_t)(niw & 0x3FFFF) * PCS + 128 + (cl << 4));
      float ww = (float)(iw >> 18) * (1.0f / 16383.0f);
#pragma unroll
      for (int j = 0; j < 8; ++j) a[j] = fmaf(bf2f(C0[j]), ww, a[j]);
      C0 = nC;
      iw = niw;
      idx = nidx;
      act = nact;
    }
    float nr = 0.f;
#pragma unroll
    for (int j = 0; j < 8; ++j) nr += a[j] * a[j];
    nr += __shfl_xor(nr, 1);
    nr += __shfl_xor(nr, 2);
    nr += __shfl_xor(nr, 4);
    nr += __shfl_xor(nr, 8);
    float inv = 1.0f / fmaxf(sqrtf(nr), 1e-12f);
    size_t o = (size_t)u * 128 + (size_t)chb;
    const float* bp = hop0 ? (base_u + o) : (res_u + o);
    float4 r0 = *(const float4*)bp;
    float4 r1 = *(const float4*)(bp + 4);
    r0.x += a[0] * inv; r0.y += a[1] * inv; r0.z += a[2] * inv; r0.w += a[3] * inv;
    r1.x += a[4] * inv; r1.y += a[5] * inv; r1.z += a[6] * inv; r1.w += a[7] * inv;
    *(float4*)(res_u + o) = r0;
    *(float4*)(res_u + o + 4) = r1;
  }
}

// ---------------- host ----------------
extern "C" void kernel_launch(void* const* d_in, const int* in_sizes, int n_in,
                              void* d_out, int out_size, void* d_ws, size_t ws_size,
                              hipStream_t stream) {
  const float* user_emb = (const float*)d_in[0];
  const float* entity_emb = (const float*)d_in[1];
  const int* edge_index = (const int*)d_in[2];
  const int* edge_type = (const int*)d_in[3];
  const int* inter_edge = (const int*)d_in[4];
  const float* inter_w = (const float*)d_in[5];
  const float* rel_emb = (const float*)d_in[6];
  const float* W_Q = (const float*)d_in[7];
  float* out = (float*)d_out;

  int n_users = in_sizes[0] / 128;
  int n_ent = in_sizes[1] / 128;
  int e_kg = in_sizes[3];
  int e_ui = in_sizes[5];
  const int* head = edge_index;
  const int* tail = edge_index + e_kg;
  const int* iu = inter_edge;         // users
  const int* ii = inter_edge + e_ui;  // items

  int n_seg = n_ent + n_users;
  int nbk = (n_seg + 511) >> SH;  // buckets of 512 segments (<=1024)

  // workspace carve
  char* wp = (char*)d_ws;
  auto take = [&](size_t bytes) {
    char* p = wp;
    wp += (bytes + 255) & ~(size_t)255;
    return p;
  };
  char* PCa = take((size_t)n_ent * PCS);
  char* PCb = take((size_t)n_ent * PCS);
  int* offs = (int*)take((size_t)(n_seg + 1) * 4);
  int* comb = (int*)take((size_t)(e_kg + e_ui) * 4);
  uint2* ebuf = (uint2*)take((size_t)(e_kg + e_ui) * 8);
  int* bh = (int*)take(4096);
  int* bbase = (int*)take(4096);
  int* bcur = (int*)take(4096);
  (void)ws_size;
  (void)n_in;
  (void)out_size;

  // bucketed CSR build (shared by both hops)
  hipMemsetAsync(bh, 0, (size_t)nbk * 4, stream);
  k_phist<<<512, NT, 0, stream>>>(head, e_kg, iu, e_ui, bh, n_ent, nbk);
  k_bscan<<<1, NT, 0, stream>>>(bh, bbase, bcur, nbk);
  k_pscatter<<<512, NT, 0, stream>>>(head, tail, edge_type, e_kg, iu, ii, inter_w, e_ui,
                                     bcur, ebuf, n_ent, nbk);
  k_fscatter<<<nbk, NT, 0, stream>>>(ebuf, bbase, bcur, offs, comb, n_seg, nbk);

  float* res_e = out;
  float* res_u = out + (size_t)n_ent * 128;
  int agg_blocks = (n_seg + 15) / 16;

  // hop 0: gemm reads fp32 entity_emb (fused cvt), agg writes nextPC only (entities)
  k_gemm<<<1024, NT, 0, stream>>>(PCa, entity_emb, W_Q, PCa, n_ent);
  k_agg<<<agg_blocks, NT, 0, stream>>>(PCa, offs, comb, rel_emb, entity_emb, user_emb,
                                       PCb, res_e, res_u, n_ent, n_seg, 1);
  // hop 1: gemm reads PCb cur-half, agg finalizes residuals
  k_gemm<<<1024, NT, 0, stream>>>(PCb, nullptr, W_Q, PCb, n_ent);
  k_agg<<<agg_blocks, NT, 0, stream>>>(PCb, offs, comb, rel_emb, entity_emb, nullptr,
                                       nullptr, res_e, res_u, n_ent, n_seg, 0);
}

// Round 13
// 443.379 us; speedup vs baseline: 1.5487x; 1.0332x over previous
//
#include <hip/hip_runtime.h>
#include <math.h>

#define NT 256
#define SH 9          // segments per bucket = 512
typedef unsigned short u16;
typedef __attribute__((ext_vector_type(8))) u16 u16x8;
typedef __attribute__((ext_vector_type(4))) u16 u16x4;
typedef __attribute__((ext_vector_type(8))) short bf16x8;
typedef __attribute__((ext_vector_type(4))) float f32x4;
typedef __attribute__((ext_vector_type(2))) float f32x2;

// PC row layout (stride 384 B): [0,128) fp8-e4m3 P (score side) | [128,384) bf16 cur (values)
// fp8 is score-side ONLY: r12 measured fp8 values -> absmax 0.043 > 0.0209 threshold.
#define PCS 384

__device__ __forceinline__ float bf2f(u16 h) {
  union { unsigned u; float f; } v;
  v.u = ((unsigned)h) << 16;
  return v.f;
}
__device__ __forceinline__ u16 f2bf(float f) {
  union { float f; unsigned u; } v;
  v.f = f;
  unsigned r = v.u + 0x7FFFu + ((v.u >> 16) & 1u);
  return (u16)(r >> 16);
}

// ---------------- bucketed CSR build ----------------
__global__ __launch_bounds__(NT) void k_phist(const int* __restrict__ head, int n_kg,
                                              const int* __restrict__ usr, int n_ui,
                                              int* __restrict__ bh, int n_ent, int nbk) {
  __shared__ int lh[1024];
  for (int i = threadIdx.x; i < nbk; i += NT) lh[i] = 0;
  __syncthreads();
  int emax = n_kg > n_ui ? n_kg : n_ui;
  int per = (emax + gridDim.x - 1) / gridDim.x;
  int lo = blockIdx.x * per;
  int hi = lo + per < emax ? lo + per : emax;
  for (int i = lo + threadIdx.x; i < hi; i += NT) {
    if (i < n_kg) atomicAdd(&lh[head[i] >> SH], 1);
    if (i < n_ui) atomicAdd(&lh[(n_ent + usr[i]) >> SH], 1);
  }
  __syncthreads();
  for (int b = threadIdx.x; b < nbk; b += NT)
    if (lh[b]) atomicAdd(&bh[b], lh[b]);
}

__global__ __launch_bounds__(NT) void k_bscan(const int* __restrict__ bh, int* __restrict__ bbase,
                                              int* __restrict__ bcur, int nbk) {
  __shared__ int sd[NT];
  int t = threadIdx.x;
  int v[4], l[4];
  int run = 0;
#pragma unroll
  for (int j = 0; j < 4; ++j) {
    int idx = t * 4 + j;
    v[j] = (idx < nbk) ? bh[idx] : 0;
    l[j] = run;
    run += v[j];
  }
  sd[t] = run;
  __syncthreads();
  for (int off = 1; off < NT; off <<= 1) {
    int x = (t >= off) ? sd[t - off] : 0;
    __syncthreads();
    sd[t] += x;
    __syncthreads();
  }
  int base = sd[t] - run;
#pragma unroll
  for (int j = 0; j < 4; ++j) {
    int idx = t * 4 + j;
    if (idx < nbk) {
      bbase[idx] = base + l[j];
      bcur[idx] = base + l[j];
    }
  }
}

__global__ __launch_bounds__(NT) void k_pscatter(
    const int* __restrict__ head, const int* __restrict__ tail, const int* __restrict__ etype, int n_kg,
    const int* __restrict__ usr, const int* __restrict__ item, const float* __restrict__ w, int n_ui,
    int* __restrict__ bcur, uint2* __restrict__ ebuf, int n_ent, int nbk) {
  __shared__ int lh[1024], lbase[1024];
  for (int i = threadIdx.x; i < nbk; i += NT) lh[i] = 0;
  __syncthreads();
  int emax = n_kg > n_ui ? n_kg : n_ui;
  int per = (emax + gridDim.x - 1) / gridDim.x;
  int lo = blockIdx.x * per;
  int hi = lo + per < emax ? lo + per : emax;
  for (int i = lo + threadIdx.x; i < hi; i += NT) {
    if (i < n_kg) atomicAdd(&lh[head[i] >> SH], 1);
    if (i < n_ui) atomicAdd(&lh[(n_ent + usr[i]) >> SH], 1);
  }
  __syncthreads();
  for (int b = threadIdx.x; b < nbk; b += NT) {
    lbase[b] = lh[b] ? atomicAdd(&bcur[b], lh[b]) : 0;
    lh[b] = 0;
  }
  __syncthreads();
  for (int i = lo + threadIdx.x; i < hi; i += NT) {
    if (i < n_kg) {
      int key = head[i];
      int b = key >> SH;
      int slot = lbase[b] + atomicAdd(&lh[b], 1);
      ebuf[slot] = (uint2){(unsigned)key, (unsigned)(tail[i] | ((etype[i] - 1) << 20))};
    }
    if (i < n_ui) {
      int key = n_ent + usr[i];
      int b = key >> SH;
      int wq = (int)(w[i] * 16383.0f + 0.5f);
      if (wq > 16383) wq = 16383;
      int slot = lbase[b] + atomicAdd(&lh[b], 1);
      ebuf[slot] = (uint2){(unsigned)key, ((unsigned)item[i]) | (((unsigned)wq) << 18)};
    }
  }
}

__global__ __launch_bounds__(NT) void k_fscatter(const uint2* __restrict__ ebuf,
                                                 const int* __restrict__ bbase,
                                                 const int* __restrict__ bcur,
                                                 int* __restrict__ offs, int* __restrict__ comb,
                                                 int n_seg, int nbk) {
  __shared__ int cnt[512];
  __shared__ int excl[512];
  __shared__ int sd[NT];
  int b = blockIdx.x;
  int t = threadIdx.x;
  int seg0 = b << SH;
  int e0 = bbase[b], e1 = bcur[b];
  cnt[t] = 0;
  cnt[t + 256] = 0;
  __syncthreads();
  for (int i = e0 + t; i < e1; i += NT) atomicAdd(&cnt[(int)ebuf[i].x - seg0], 1);
  __syncthreads();
  int v0 = cnt[2 * t], v1 = cnt[2 * t + 1];
  int pair = v0 + v1;
  sd[t] = pair;
  __syncthreads();
  for (int off = 1; off < NT; off <<= 1) {
    int x = (t >= off) ? sd[t - off] : 0;
    __syncthreads();
    sd[t] += x;
    __syncthreads();
  }
  int before = sd[t] - pair;
  excl[2 * t] = before;
  excl[2 * t + 1] = before + v0;
  __syncthreads();
#pragma unroll
  for (int j = 0; j < 2; ++j) {
    int s = t + j * 256;
    int gs = seg0 + s;
    if (gs < n_seg) offs[gs] = e0 + excl[s];
  }
  if (b == nbk - 1 && t == 0) offs[n_seg] = e1;
  __syncthreads();
  cnt[2 * t] = 0;
  cnt[2 * t + 1] = 0;
  __syncthreads();
  for (int i = e0 + t; i < e1; i += NT) {
    uint2 v = ebuf[i];
    int s = (int)v.x - seg0;
    int p = atomicAdd(&cnt[s], 1);
    comb[e0 + excl[s] + p] = (int)v.y;
  }
}

// ---------------- MFMA GEMM: P-half(PC, fp8) = A @ W ----------------
// hop0 (A32 != nullptr): A from fp32 entity_emb; also writes bf16 cur-half.
// hop1: A = cur-half (bf16) of PCin (hop0 normalized output).
__global__ __launch_bounds__(NT) void k_gemm(const char* __restrict__ PCin, const float* __restrict__ A32,
                                             const float* __restrict__ W, char* __restrict__ PCout, int M) {
  __shared__ u16 WT[128 * 136];  // W^T[n][k] bf16
  for (int i = threadIdx.x; i < 128 * 32; i += NT) {
    int n = i & 127, k4 = (i >> 7) << 2;
    u16x4 o = {f2bf(W[(k4 + 0) * 128 + n]), f2bf(W[(k4 + 1) * 128 + n]),
               f2bf(W[(k4 + 2) * 128 + n]), f2bf(W[(k4 + 3) * 128 + n])};
    *(u16x4*)&WT[n * 136 + k4] = o;
  }
  __syncthreads();
  int lane = threadIdx.x & 63;
  int l15 = lane & 15, l4 = lane >> 4;
  int wave = blockIdx.x * (NT / 64) + (threadIdx.x >> 6);
  int nw = gridDim.x * (NT / 64);
  int ntiles = (M + 15) >> 4;
  for (int tile = wave; tile < ntiles; tile += nw) {
    long row0 = (long)tile * 16;
    long myrow = row0 + l15;
    bool rowok = myrow < M;
    long ar = rowok ? myrow : (long)(M - 1);
    bf16x8 af[4];
    if (A32) {
      const float* arow = A32 + ar * 128;
#pragma unroll
      for (int kk = 0; kk < 4; ++kk) {
        const float* p = arow + kk * 32 + l4 * 8;
        float4 f0 = *(const float4*)p;
        float4 f1 = *(const float4*)(p + 4);
        u16x8 t = {f2bf(f0.x), f2bf(f0.y), f2bf(f0.z), f2bf(f0.w),
                   f2bf(f1.x), f2bf(f1.y), f2bf(f1.z), f2bf(f1.w)};
        af[kk] = *(bf16x8*)&t;
        if (rowok) *(u16x8*)(PCout + ar * PCS + 128 + kk * 64 + l4 * 16) = t;
      }
    } else {
      const char* arow = PCin + ar * PCS + 128;  // cur half (bf16)
#pragma unroll
      for (int kk = 0; kk < 4; ++kk) af[kk] = *(const bf16x8*)(arow + kk * 64 + l4 * 16);
    }
    f32x4 acc[8];
#pragma unroll
    for (int nt = 0; nt < 8; ++nt) acc[nt] = (f32x4){0.f, 0.f, 0.f, 0.f};
#pragma unroll
    for (int kk = 0; kk < 4; ++kk) {
#pragma unroll
      for (int nt = 0; nt < 8; ++nt) {
        bf16x8 bf = *(const bf16x8*)&WT[(nt * 16 + l15) * 136 + kk * 32 + l4 * 8];
        acc[nt] = __builtin_amdgcn_mfma_f32_16x16x32_bf16(af[kk], bf, acc[nt], 0, 0, 0);
      }
    }
#pragma unroll
    for (int nt = 0; nt < 8; ++nt) {
#pragma unroll
      for (int j = 0; j < 4; ++j) {
        long row = row0 + l4 * 4 + j;
        if (row < M) {
          float v = acc[nt][j];
          int pk = __builtin_amdgcn_cvt_pk_fp8_f32(v, v, 0, false);
          PCout[row * PCS + nt * 16 + l15] = (char)(pk & 0xFF);
        }
      }
    }
  }
}

// ---------------- fused segment aggregate (entity attention + user) ----------------
// One 16-lane unit per segment; 4 segments per wave, natural order; dist-1
// rotating prefetch. fp8 score gathers (8B/lane), bf16 value gathers (16B/lane).
// Deferred residuals: hop0 writes bf16 hop-0 outputs (PCb cur-half for entities,
// G0u for users); hop1 computes res = base + g0 + g1 (one fp32 write, no RMW).
__global__ __launch_bounds__(NT) void k_agg(
    const char* __restrict__ PCc, const int* __restrict__ offs, const int* __restrict__ comb,
    const float* __restrict__ rel_emb, const float* __restrict__ base_e,
    const float* __restrict__ base_u, char* __restrict__ nextPC, u16* __restrict__ G0u,
    float* __restrict__ res_e, float* __restrict__ res_u, int n_ent, int n_seg, int hop0) {
  __shared__ float rel[9 * 128];
  for (int i = threadIdx.x; i < 9 * 128; i += NT) rel[i] = rel_emb[i];
  __syncthreads();
  int lane = threadIdx.x & 63;
  int cl = lane & 15;    // channel chunk (8 ch); head = cl>>3
  int chb = cl * 8;
  int sseg = (((blockIdx.x * NT + threadIdx.x) >> 6) << 2) + (lane >> 4);
  if (sseg >= n_seg) return;
  int beg = offs[sseg], end = offs[sseg + 1];

  if (sseg < n_ent) {
    // ---- entity attention path ----
    uint2 qv = *(const uint2*)(PCc + (size_t)sseg * PCS + (cl << 3));
    f32x2 q01 = __builtin_amdgcn_cvt_pk_f32_fp8((int)qv.x, false);
    f32x2 q23 = __builtin_amdgcn_cvt_pk_f32_fp8((int)qv.x, true);
    f32x2 q45 = __builtin_amdgcn_cvt_pk_f32_fp8((int)qv.y, false);
    f32x2 q67 = __builtin_amdgcn_cvt_pk_f32_fp8((int)qv.y, true);
    float q[8] = {q01[0] * 0.125f, q01[1] * 0.125f, q23[0] * 0.125f, q23[1] * 0.125f,
                  q45[0] * 0.125f, q45[1] * 0.125f, q67[0] * 0.125f, q67[1] * 0.125f};
    float s = 0.f;
    float a[8] = {0.f, 0.f, 0.f, 0.f, 0.f, 0.f, 0.f, 0.f};
    int idx = beg;
    bool act = idx < end;
    unsigned te = act ? (unsigned)comb[idx] : 0u;
    const char* rowp = PCc + (size_t)(te & 0xFFFFF) * PCS;
    uint2 P0 = act ? *(const uint2*)(rowp + (cl << 3)) : (uint2){0, 0};
    u16x8 C0 = act ? *(const u16x8*)(rowp + 128 + (cl << 4)) : (u16x8){};
    while (act) {
      int nidx = idx + 1;
      bool nact = nidx < end;
      unsigned nte = nact ? (unsigned)comb[nidx] : 0u;
      const char* nrp = PCc + (size_t)(nte & 0xFFFFF) * PCS;
      uint2 nP = *(const uint2*)(nrp + (cl << 3));
      u16x8 nC = *(const u16x8*)(nrp + 128 + (cl << 4));
      const float* rp = &rel[(te >> 20) * 128 + chb];
      float4 rA = *(const float4*)rp;
      float4 rB = *(const float4*)(rp + 4);
      f32x2 p01 = __builtin_amdgcn_cvt_pk_f32_fp8((int)P0.x, false);
      f32x2 p23 = __builtin_amdgcn_cvt_pk_f32_fp8((int)P0.x, true);
      f32x2 p45 = __builtin_amdgcn_cvt_pk_f32_fp8((int)P0.y, false);
      f32x2 p67 = __builtin_amdgcn_cvt_pk_f32_fp8((int)P0.y, true);
      float pp = q[0] * p01[0] * rA.x + q[1] * p01[1] * rA.y +
                 q[2] * p23[0] * rA.z + q[3] * p23[1] * rA.w +
                 q[4] * p45[0] * rB.x + q[5] * p45[1] * rB.y +
                 q[6] * p67[0] * rB.z + q[7] * p67[1] * rB.w;
      pp += __shfl_xor(pp, 1);
      pp += __shfl_xor(pp, 2);
      pp += __shfl_xor(pp, 4);  // per-head score on its own lanes
      float e = __expf(pp);
      s += e;
      a[0] = fmaf(bf2f(C0[0]) * rA.x, e, a[0]);
      a[1] = fmaf(bf2f(C0[1]) * rA.y, e, a[1]);
      a[2] = fmaf(bf2f(C0[2]) * rA.z, e, a[2]);
      a[3] = fmaf(bf2f(C0[3]) * rA.w, e, a[3]);
      a[4] = fmaf(bf2f(C0[4]) * rB.x, e, a[4]);
      a[5] = fmaf(bf2f(C0[5]) * rB.y, e, a[5]);
      a[6] = fmaf(bf2f(C0[6]) * rB.z, e, a[6]);
      a[7] = fmaf(bf2f(C0[7]) * rB.w, e, a[7]);
      P0 = nP;
      C0 = nC;
      te = nte;
      idx = nidx;
      act = nact;
    }
    float invs = 1.0f / fmaxf(s, 1e-16f);
    float gv[8];
    float nr = 0.f;
#pragma unroll
    for (int j = 0; j < 8; ++j) {
      gv[j] = a[j] * invs;
      nr += gv[j] * gv[j];
    }
    nr += __shfl_xor(nr, 1);
    nr += __shfl_xor(nr, 2);
    nr += __shfl_xor(nr, 4);
    nr += __shfl_xor(nr, 8);  // norm spans both heads
    float inv = 1.0f / fmaxf(sqrtf(nr), 1e-12f);
#pragma unroll
    for (int j = 0; j < 8; ++j) gv[j] *= inv;
    if (hop0) {
      u16x8 o;
#pragma unroll
      for (int j = 0; j < 8; ++j) o[j] = f2bf(gv[j]);
      *(u16x8*)(nextPC + (size_t)sseg * PCS + 128 + (cl << 4)) = o;
    } else {
      u16x8 g0 = *(const u16x8*)(PCc + (size_t)sseg * PCS + 128 + (cl << 4));
      size_t o4 = (size_t)sseg * 128 + (size_t)chb;
      float4 b0 = *(const float4*)(base_e + o4);
      float4 b1 = *(const float4*)(base_e + o4 + 4);
      float4 w0 = {b0.x + bf2f(g0[0]) + gv[0], b0.y + bf2f(g0[1]) + gv[1],
                   b0.z + bf2f(g0[2]) + gv[2], b0.w + bf2f(g0[3]) + gv[3]};
      float4 w1 = {b1.x + bf2f(g0[4]) + gv[4], b1.y + bf2f(g0[5]) + gv[5],
                   b1.z + bf2f(g0[6]) + gv[6], b1.w + bf2f(g0[7]) + gv[7]};
      *(float4*)(res_e + o4) = w0;
      *(float4*)(res_e + o4 + 4) = w1;
    }
  } else {
    // ---- user aggregate path ----
    int u = sseg - n_ent;
    float a[8] = {0.f, 0.f, 0.f, 0.f, 0.f, 0.f, 0.f, 0.f};
    int idx = beg;
    bool act = idx < end;
    unsigned iw = act ? (unsigned)comb[idx] : 0u;
    u16x8 C0 = act ? *(const u16x8*)(PCc + (size_t)(iw & 0x3FFFF) * PCS + 128 + (cl << 4))
                   : (u16x8){};
    while (act) {
      int nidx = idx + 1;
      bool nact = nidx < end;
      unsigned niw = nact ? (unsigned)comb[nidx] : 0u;
      u16x8 nC = *(const u16x8*)(PCc + (size_t)(niw & 0x3FFFF) * PCS + 128 + (cl << 4));
      float ww = (float)(iw >> 18) * (1.0f / 16383.0f);
#pragma unroll
      for (int j = 0; j < 8; ++j) a[j] = fmaf(bf2f(C0[j]), ww, a[j]);
      C0 = nC;
      iw = niw;
      idx = nidx;
      act = nact;
    }
    float nr = 0.f;
#pragma unroll
    for (int j = 0; j < 8; ++j) nr += a[j] * a[j];
    nr += __shfl_xor(nr, 1);
    nr += __shfl_xor(nr, 2);
    nr += __shfl_xor(nr, 4);
    nr += __shfl_xor(nr, 8);
    float inv = 1.0f / fmaxf(sqrtf(nr), 1e-12f);
#pragma unroll
    for (int j = 0; j < 8; ++j) a[j] *= inv;
    if (hop0) {
      u16x8 o;
#pragma unroll
      for (int j = 0; j < 8; ++j) o[j] = f2bf(a[j]);
      *(u16x8*)(G0u + (size_t)u * 128 + chb) = o;
    } else {
      u16x8 u0 = *(const u16x8*)(G0u + (size_t)u * 128 + chb);
      size_t o = (size_t)u * 128 + (size_t)chb;
      float4 b0 = *(const float4*)(base_u + o);
      float4 b1 = *(const float4*)(base_u + o + 4);
      float4 w0 = {b0.x + bf2f(u0[0]) + a[0], b0.y + bf2f(u0[1]) + a[1],
                   b0.z + bf2f(u0[2]) + a[2], b0.w + bf2f(u0[3]) + a[3]};
      float4 w1 = {b1.x + bf2f(u0[4]) + a[4], b1.y + bf2f(u0[5]) + a[5],
                   b1.z + bf2f(u0[6]) + a[6], b1.w + bf2f(u0[7]) + a[7]};
      *(float4*)(res_u + o) = w0;
      *(float4*)(res_u + o + 4) = w1;
    }
  }
}

// ---------------- host ----------------
extern "C" void kernel_launch(void* const* d_in, const int* in_sizes, int n_in,
                              void* d_out, int out_size, void* d_ws, size_t ws_size,
                              hipStream_t stream) {
  const float* user_emb = (const float*)d_in[0];
  const float* entity_emb = (const float*)d_in[1];
  const int* edge_index = (const int*)d_in[2];
  const int* edge_type = (const int*)d_in[3];
  const int* inter_edge = (const int*)d_in[4];
  const float* inter_w = (const float*)d_in[5];
  const float* rel_emb = (const float*)d_in[6];
  const float* W_Q = (const float*)d_in[7];
  float* out = (float*)d_out;

  int n_users = in_sizes[0] / 128;
  int n_ent = in_sizes[1] / 128;
  int e_kg = in_sizes[3];
  int e_ui = in_sizes[5];
  const int* head = edge_index;
  const int* tail = edge_index + e_kg;
  const int* iu = inter_edge;         // users
  const int* ii = inter_edge + e_ui;  // items

  int n_seg = n_ent + n_users;
  int nbk = (n_seg + 511) >> SH;  // buckets of 512 segments (<=1024)

  // workspace carve
  char* wp = (char*)d_ws;
  auto take = [&](size_t bytes) {
    char* p = wp;
    wp += (bytes + 255) & ~(size_t)255;
    return p;
  };
  char* PCa = take((size_t)n_ent * PCS);
  char* PCb = take((size_t)n_ent * PCS);
  u16* G0u = (u16*)take((size_t)n_users * 128 * 2);
  int* offs = (int*)take((size_t)(n_seg + 1) * 4);
  int* comb = (int*)take((size_t)(e_kg + e_ui) * 4);
  uint2* ebuf = (uint2*)take((size_t)(e_kg + e_ui) * 8);
  int* bh = (int*)take(4096);
  int* bbase = (int*)take(4096);
  int* bcur = (int*)take(4096);
  (void)ws_size;
  (void)n_in;
  (void)out_size;

  // bucketed CSR build (shared by both hops)
  hipMemsetAsync(bh, 0, (size_t)nbk * 4, stream);
  k_phist<<<512, NT, 0, stream>>>(head, e_kg, iu, e_ui, bh, n_ent, nbk);
  k_bscan<<<1, NT, 0, stream>>>(bh, bbase, bcur, nbk);
  k_pscatter<<<512, NT, 0, stream>>>(head, tail, edge_type, e_kg, iu, ii, inter_w, e_ui,
                                     bcur, ebuf, n_ent, nbk);
  k_fscatter<<<nbk, NT, 0, stream>>>(ebuf, bbase, bcur, offs, comb, n_seg, nbk);

  float* res_e = out;
  float* res_u = out + (size_t)n_ent * 128;
  int agg_blocks = (n_seg + 15) / 16;

  // hop 0: gemm reads fp32 entity_emb (fused cvt -> fp8 P + bf16 cur); agg
  // writes bf16 hop-0 outputs (PCb cur-half for entities, G0u for users)
  k_gemm<<<1024, NT, 0, stream>>>(PCa, entity_emb, W_Q, PCa, n_ent);
  k_agg<<<agg_blocks, NT, 0, stream>>>(PCa, offs, comb, rel_emb, entity_emb, user_emb,
                                       PCb, G0u, res_e, res_u, n_ent, n_seg, 1);
  // hop 1: gemm reads PCb cur-half (bf16); agg finalizes res = base + g0 + g1
  k_gemm<<<1024, NT, 0, stream>>>(PCb, nullptr, W_Q, PCb, n_ent);
  k_agg<<<agg_blocks, NT, 0, stream>>>(PCb, offs, comb, rel_emb, entity_emb, user_emb,
                                       nullptr, G0u, res_e, res_u, n_ent, n_seg, 0);
}